// Round 18
// baseline (215.894 us; speedup 1.0000x reference)
//
#include <hip/hip_runtime.h>

constexpr int Sc = 4096, Dc = 64;
constexpr int BH = 128;
constexpr int MM = Dc * Dc;               // 4096 floats of M per (bh)
constexpr int QT = 128;                   // q-rows per block in k3

using sh8 = __attribute__((ext_vector_type(8))) short;
using f32x4 = __attribute__((ext_vector_type(4))) float;
typedef __attribute__((address_space(1))) const unsigned int as1_u32;
typedef __attribute__((address_space(3))) unsigned int as3_u32;

__device__ __forceinline__ unsigned int packbf2(float lo, float hi) {
  // two RNE float->bf16 packed into one dword (bit-identical to R9..R17 pass)
  unsigned int a = __builtin_bit_cast(unsigned int, lo);
  unsigned int b = __builtin_bit_cast(unsigned int, hi);
  a = (a + 0x7fffu + ((a >> 16) & 1u)) >> 16;
  b = (b + 0x7fffu + ((b >> 16) & 1u)) & 0xffff0000u;
  return a | b;
}

// ---- Kernel 1 (primary): burst-staged 2-phase; allocator pinned to 2 waves/EU ----
// R16/R17 both spilled at VGPR=88: the allocator targets ~6 waves/SIMD on its own
// heuristic and spills burst payloads to get there. amdgpu_waves_per_eu(2,2)
// removes that incentive (2 blocks/CU is the LDS limit anyway) -> 256-VGPR budget,
// b1 payload (64 VGPR) stays in registers, loads land under phase-0 compute.
__global__ __launch_bounds__(256)
__attribute__((amdgpu_waves_per_eu(2, 2)))
void k1_pair(const float* __restrict__ K,
             const float* __restrict__ V,
             float* __restrict__ Pm,
             double* __restrict__ Pz) {
  const int blk = blockIdx.x, bh = blk >> 4, ck = blk & 15;   // 16 blocks/bh
  const int tid = threadIdx.x, w = tid >> 6, l = tid & 63;
  const int g = l >> 4, c = l & 15;

  const size_t base = ((size_t)bh * Sc + (size_t)ck * 256) * Dc;  // 256 rows/block
  const float4* gk4 = (const float4*)(K + base);   // 4096 float4
  const float4* gv4 = (const float4*)(V + base);

  __shared__ __align__(16) float smem[2 * 8192];   // K 32KB | V 32KB (one phase)
  float4* sK4 = (float4*)smem;
  float4* sV4 = (float4*)(smem + 8192);

  f32x4 acc[4];
  #pragma unroll
  for (int i = 0; i < 4; ++i) acc[i] = (f32x4){0.f, 0.f, 0.f, 0.f};
  double zacc = 0.0;

  // burst 0 (phase-0 rows 0..127): 16 independent float4 loads, staged to LDS
  {
    float4 b0k[8], b0v[8];
    #pragma unroll
    for (int j = 0; j < 8; ++j) b0k[j] = gk4[tid + j * 256];
    #pragma unroll
    for (int j = 0; j < 8; ++j) b0v[j] = gv4[tid + j * 256];
    #pragma unroll
    for (int j = 0; j < 8; ++j) { sK4[tid + j * 256] = b0k[j]; sV4[tid + j * 256] = b0v[j]; }
  }
  asm volatile("s_waitcnt lgkmcnt(0)" ::: "memory");
  __builtin_amdgcn_s_barrier();

  // burst 1 (phase-1 rows 128..255): issue now, consume after phase-0 compute
  float4 b1k[8], b1v[8];
  #pragma unroll
  for (int j = 0; j < 8; ++j) b1k[j] = gk4[2048 + tid + j * 256];
  #pragma unroll
  for (int j = 0; j < 8; ++j) b1v[j] = gv4[2048 + tid + j * 256];
  __builtin_amdgcn_sched_barrier(0);   // pin issue before the compute block

#define K1_COMPUTE()                                                          \
  {                                                                           \
    _Pragma("unroll")                                                         \
    for (int ks = 0; ks < 4; ++ks) {                                          \
      float ak[8];                                                            \
      _Pragma("unroll")                                                       \
      for (int j = 0; j < 8; ++j)                                             \
        ak[j] = smem[(ks * 32 + 8 * g + j) * 64 + 16 * w + c];                \
      unsigned int au[4];                                                     \
      _Pragma("unroll")                                                       \
      for (int j = 0; j < 4; ++j) au[j] = packbf2(ak[2 * j], ak[2 * j + 1]);  \
      const sh8 afr = __builtin_bit_cast(sh8, *(const uint4*)au);             \
      _Pragma("unroll")                                                       \
      for (int et = 0; et < 4; ++et) {                                        \
        float bv[8];                                                          \
        _Pragma("unroll")                                                     \
        for (int j = 0; j < 8; ++j)                                           \
          bv[j] = smem[8192 + (ks * 32 + 8 * g + j) * 64 + 16 * et + c];      \
        unsigned int bu[4];                                                   \
        _Pragma("unroll")                                                     \
        for (int j = 0; j < 4; ++j) bu[j] = packbf2(bv[2 * j], bv[2 * j + 1]);\
        const sh8 bfr = __builtin_bit_cast(sh8, *(const uint4*)bu);           \
        acc[et] = __builtin_amdgcn_mfma_f32_16x16x32_bf16(afr, bfr, acc[et], 0, 0, 0); \
      }                                                                       \
    }                                                                         \
    _Pragma("unroll")                                                         \
    for (int r = 0; r < 32; ++r) zacc += (double)smem[(w * 32 + r) * 64 + l]; \
  }

  K1_COMPUTE()        // phase 0 (b1 loads land underneath)

  __syncthreads();    // phase-0 reads done (b1 has had a full compute phase)
  #pragma unroll
  for (int j = 0; j < 8; ++j) { sK4[tid + j * 256] = b1k[j]; sV4[tid + j * 256] = b1v[j]; }
  __syncthreads();

  K1_COMPUTE()        // phase 1
#undef K1_COMPUTE

  // Pm partial: D layout col=lane&15 -> e=16et+c, row=(lane>>4)*4+r -> d=16w+4g+r
  float* pd = Pm + ((size_t)ck * BH + bh) * MM;
  #pragma unroll
  for (int et = 0; et < 4; ++et)
    #pragma unroll
    for (int r = 0; r < 4; ++r)
      pd[(16 * w + 4 * g + r) * 64 + 16 * et + c] = acc[et][r];

  // z partial p = ck*4 + w, component d = l
  Pz[((size_t)(ck * 4 + w) * BH + bh) * Dc + l] = zacc;
}

// ---- Kernel 1 (fallback, R15 verbatim: gll 2-phase, SS=8) ----
__global__ __launch_bounds__(256) void k1_v15(const float* __restrict__ K,
                                              const float* __restrict__ V,
                                              float* __restrict__ Pm,
                                              double* __restrict__ Pz) {
  constexpr int SS = 8, CHUNK = Sc / SS, SROWS = 32, NST = CHUNK / SROWS;
  const int blk = blockIdx.x, bh = blk >> 3, ck = blk & 7;
  const int tid = threadIdx.x, w = tid >> 6, l = tid & 63;
  const int g = l >> 4, c = l & 15;
  const size_t base = ((size_t)bh * Sc + (size_t)ck * CHUNK) * Dc;
  const float* Kg = K + base;
  const float* Vg = V + base;
  __shared__ __align__(16) float smem[2 * 4096];
  const int lofs = w * 512 + l * 4;
  f32x4 acc[4];
  #pragma unroll
  for (int i = 0; i < 4; ++i) acc[i] = (f32x4){0.f, 0.f, 0.f, 0.f};
  double zacc = 0.0;
#define K1_ISSUE(T, BUF)                                                         \
  {                                                                              \
    const float* gk_ = Kg + (size_t)(T) * 2048 + lofs;                           \
    const float* gv_ = Vg + (size_t)(T) * 2048 + lofs;                           \
    float* lk_ = &smem[(BUF) * 4096 + w * 512];                                  \
    float* lv_ = &smem[(BUF) * 4096 + 2048 + w * 512];                           \
    __builtin_amdgcn_global_load_lds((as1_u32*)gk_,         (as3_u32*)lk_,         16, 0, 0); \
    __builtin_amdgcn_global_load_lds((as1_u32*)(gk_ + 256), (as3_u32*)(lk_ + 256), 16, 0, 0); \
    __builtin_amdgcn_global_load_lds((as1_u32*)gv_,         (as3_u32*)lv_,         16, 0, 0); \
    __builtin_amdgcn_global_load_lds((as1_u32*)(gv_ + 256), (as3_u32*)(lv_ + 256), 16, 0, 0); \
  }
  K1_ISSUE(0, 0)
  for (int t = 0; t < NST; ++t) {
    const int buf = t & 1;
    asm volatile("s_waitcnt vmcnt(0)" ::: "memory");
    asm volatile("s_waitcnt lgkmcnt(0)" ::: "memory");
    __builtin_amdgcn_s_barrier();
    if (t + 1 < NST) K1_ISSUE(t + 1, buf ^ 1)
    const float* bK = &smem[buf * 4096];
    const float* bV = &smem[buf * 4096 + 2048];
    #pragma unroll
    for (int r = 0; r < 8; ++r) zacc += (double)bK[(8 * w + r) * 64 + l];
    float ak[8];
    #pragma unroll
    for (int j = 0; j < 8; ++j) ak[j] = bK[(8 * g + j) * 64 + 16 * w + c];
    unsigned int au[4];
    #pragma unroll
    for (int j = 0; j < 4; ++j) au[j] = packbf2(ak[2 * j], ak[2 * j + 1]);
    const sh8 afr = __builtin_bit_cast(sh8, *(const uint4*)au);
    #pragma unroll
    for (int et = 0; et < 4; ++et) {
      float bv[8];
      #pragma unroll
      for (int j = 0; j < 8; ++j) bv[j] = bV[(8 * g + j) * 64 + 16 * et + c];
      unsigned int bu[4];
      #pragma unroll
      for (int j = 0; j < 4; ++j) bu[j] = packbf2(bv[2 * j], bv[2 * j + 1]);
      const sh8 bfr = __builtin_bit_cast(sh8, *(const uint4*)bu);
      acc[et] = __builtin_amdgcn_mfma_f32_16x16x32_bf16(afr, bfr, acc[et], 0, 0, 0);
    }
  }
#undef K1_ISSUE
  float* pd = Pm + ((size_t)ck * BH + bh) * MM;
  #pragma unroll
  for (int et = 0; et < 4; ++et)
    #pragma unroll
    for (int r = 0; r < 4; ++r)
      pd[(16 * w + 4 * g + r) * 64 + 16 * et + c] = acc[et][r];
  Pz[((size_t)(ck * 4 + w) * BH + bh) * Dc + l] = zacc;
}

// ---- Kernel 2: reduce M partials (f32); z = f64 exact sum ROUNDED TO F32 ----
__global__ __launch_bounds__(256) void k2_reduce(const float* __restrict__ Pm,
                                                 const double* __restrict__ Pz,
                                                 float* __restrict__ Fm,
                                                 float* __restrict__ Fz,
                                                 int ss, int nzp) {
  const int i = blockIdx.x * 256 + threadIdx.x;
  const int nm = BH * MM;
  if (i < nm) {
    float s = 0.f;
    for (int cc = 0; cc < ss; ++cc) s += Pm[(size_t)cc * nm + i];
    Fm[i] = s;
  }
  const int nz = BH * Dc;
  if (i < nz) {
    double s = 0.0;
    for (int cc = 0; cc < nzp; ++cc) s += Pz[(size_t)cc * nz + i];
    Fz[i] = (float)s;   // f32 intermediate matches np bitwise
  }
}

// ---- Kernel 3: out = (q @ M) / (q . z_f32 + eps); 4 rows x 8 cols per thread ----
__global__ __launch_bounds__(256) void k3_retrieve(const float* __restrict__ Q,
                                                   const float* __restrict__ Fm,
                                                   const float* __restrict__ Fz,
                                                   float* __restrict__ O) {
  const int blk = blockIdx.x;             // BH * (Sc/QT) = 128*32
  const int bh = blk >> 5;
  const int row0 = (blk & 31) * QT;

  __shared__ __align__(16) float lm[Dc][Dc];     // 16 KB
  __shared__ __align__(16) float lq[QT][68];     // padded: row stride 68 floats
  __shared__ __align__(16) float lz[Dc];         // f32 z (the np intermediate)

  const int tid = threadIdx.x;

  const float4* gm4 = (const float4*)(Fm + (size_t)bh * MM);
  float4* lm4 = (float4*)&lm[0][0];
  #pragma unroll
  for (int j = 0; j < 4; ++j) lm4[tid + j * 256] = gm4[tid + j * 256];
  if (tid < Dc) lz[tid] = Fz[(size_t)bh * Dc + tid];

  const float4* gq4 = (const float4*)(Q + ((size_t)bh * Sc + row0) * Dc);
  #pragma unroll
  for (int j = 0; j < 8; ++j) {
    const int i4 = tid + j * 256;
    const float4 v = gq4[i4];
    const int f = i4 * 4;
    *(float4*)&lq[f >> 6][f & 63] = v;
  }
  __syncthreads();

  const int rg = tid >> 3;       // 0..31 -> row quad
  const int cg = tid & 7;        // 0..7  -> 8-col block
  const int r0 = rg * 4;
  const int e0 = cg * 8;

  float acc[4][8] = {};
  double den[4] = {0.0, 0.0, 0.0, 0.0};

  #pragma unroll
  for (int ds = 0; ds < 16; ++ds) {
    const int d0 = ds * 4;
    const float4 z4 = *(const float4*)&lz[d0];
    const float* zf = (const float*)&z4;
    float4 q4[4];
    #pragma unroll
    for (int r = 0; r < 4; ++r) q4[r] = *(const float4*)&lq[r0 + r][d0];
    const float* qf[4] = {(const float*)&q4[0], (const float*)&q4[1],
                          (const float*)&q4[2], (const float*)&q4[3]};
    #pragma unroll
    for (int i = 0; i < 4; ++i) {
      const float4 ma = *(const float4*)&lm[d0 + i][e0];
      const float4 mb = *(const float4*)&lm[d0 + i][e0 + 4];
      const float mf[8] = {ma.x, ma.y, ma.z, ma.w, mb.x, mb.y, mb.z, mb.w};
      const double zd = (double)zf[i];
      #pragma unroll
      for (int r = 0; r < 4; ++r) {
        const float qs = qf[r][i];
        den[r] += (double)qs * zd;
        #pragma unroll
        for (int j = 0; j < 8; ++j)
          acc[r][j] = fmaf(qs, mf[j], acc[r][j]);
      }
    }
  }

  #pragma unroll
  for (int r = 0; r < 4; ++r) {
    const double iv = 1.0 / (den[r] + 1e-6);
    float* go = O + ((size_t)bh * Sc + row0 + r0 + r) * Dc + e0;
    ((float4*)go)[0] = make_float4((float)((double)acc[r][0] * iv),
                                   (float)((double)acc[r][1] * iv),
                                   (float)((double)acc[r][2] * iv),
                                   (float)((double)acc[r][3] * iv));
    ((float4*)go)[1] = make_float4((float)((double)acc[r][4] * iv),
                                   (float)((double)acc[r][5] * iv),
                                   (float)((double)acc[r][6] * iv),
                                   (float)((double)acc[r][7] * iv));
  }
}

extern "C" void kernel_launch(void* const* d_in, const int* in_sizes, int n_in,
                              void* d_out, int out_size, void* d_ws, size_t ws_size,
                              hipStream_t stream) {
  const float* K = (const float*)d_in[0];   // keys    [B,H,S,D]
  const float* V = (const float*)d_in[1];   // values
  const float* Q = (const float*)d_in[2];   // queries
  float* O = (float*)d_out;                 // [B,H,S,D]

  // primary path footprint (== R14/R16/R17's ss=16 layout): ~39.9 MB
  const size_t need16 = (size_t)16 * BH * MM * 4 + (size_t)BH * MM * 4 +
                        (size_t)64 * BH * Dc * 8 + (size_t)BH * Dc * 4;
  const int ss = (ws_size >= need16) ? 16 : 8;
  const int nzp = ss * 4;

  float* Pm = (float*)d_ws;                                  // ss*BH*MM floats
  float* Fm = Pm + (size_t)ss * BH * MM;                     // BH*MM floats
  double* Pz = (double*)(Fm + (size_t)BH * MM);              // nzp*BH*Dc doubles
  float* Fz = (float*)(Pz + (size_t)nzp * BH * Dc);          // BH*Dc floats

  if (ss == 16)
    hipLaunchKernelGGL(k1_pair, dim3(BH * 16), dim3(256), 0, stream, K, V, Pm, Pz);
  else
    hipLaunchKernelGGL(k1_v15, dim3(BH * 8), dim3(256), 0, stream, K, V, Pm, Pz);
  hipLaunchKernelGGL(k2_reduce, dim3((BH * MM + 255) / 256), dim3(256), 0, stream,
                     Pm, Pz, Fm, Fz, ss, nzp);
  hipLaunchKernelGGL(k3_retrieve, dim3(BH * (Sc / QT)), dim3(256), 0, stream, Q, Fm, Fz, O);
}

// Round 19
// 180.885 us; speedup vs baseline: 1.1935x; 1.1935x over previous
//
#include <hip/hip_runtime.h>

constexpr int Sc = 4096, Dc = 64;
constexpr int BH = 128;
constexpr int MM = Dc * Dc;               // 4096 floats of M per (bh)
constexpr int QT = 128;                   // q-rows per block in k3

using sh8 = __attribute__((ext_vector_type(8))) short;
using f32x4 = __attribute__((ext_vector_type(4))) float;
typedef __attribute__((address_space(1))) const unsigned int as1_u32;
typedef __attribute__((address_space(3))) unsigned int as3_u32;

__device__ __forceinline__ unsigned int packbf2(float lo, float hi) {
  // two RNE float->bf16 packed into one dword (bit-identical to R9..R18 pass)
  unsigned int a = __builtin_bit_cast(unsigned int, lo);
  unsigned int b = __builtin_bit_cast(unsigned int, hi);
  a = (a + 0x7fffu + ((a >> 16) & 1u)) >> 16;
  b = (b + 0x7fffu + ((b >> 16) & 1u)) & 0xffff0000u;
  return a | b;
}

// ---- Kernel 1 (primary): one-shot gll burst staging, 2 x 128-row phases ----
// The burst issue-profile (R16-18: 3.1 TB/s even while spilling) combined with
// global_load_lds (R15: correct, ZERO VGPR payload -> allocator can't spill it).
// 16 gll/wave per phase = 64 KB in flight per block, drained ONCE per phase.
// 2 blocks/CU alternate fill/compute -> memory stays saturated.
__global__ __launch_bounds__(256) void k1_burst(const float* __restrict__ K,
                                                const float* __restrict__ V,
                                                float* __restrict__ Pm,
                                                double* __restrict__ Pz) {
  const int blk = blockIdx.x, bh = blk >> 4, ck = blk & 15;   // 16 blocks/bh
  const int tid = threadIdx.x, w = tid >> 6, l = tid & 63;
  const int g = l >> 4, c = l & 15;

  const size_t base = ((size_t)bh * Sc + (size_t)ck * 256) * Dc;  // 256 rows/block
  const float* Kg = K + base;
  const float* Vg = V + base;

  __shared__ __align__(16) float smem[16384];   // 64 KB: K 32KB | V 32KB (one phase)

  f32x4 acc[4];
  #pragma unroll
  for (int i = 0; i < 4; ++i) acc[i] = (f32x4){0.f, 0.f, 0.f, 0.f};
  double zacc = 0.0;

  // 16 back-to-back gll per wave: 8 K chunks + 8 V chunks (1 KB each, linear LDS)
#define K1_ISSUE(PH)                                                            \
  {                                                                             \
    const float* gk_ = Kg + (PH) * 8192;                                        \
    const float* gv_ = Vg + (PH) * 8192;                                        \
    _Pragma("unroll")                                                           \
    for (int j = 0; j < 8; ++j) {                                               \
      const int cb = (w * 8 + j) * 256;      /* chunk base (floats) */          \
      __builtin_amdgcn_global_load_lds((as1_u32*)(gk_ + cb + l * 4),            \
                                       (as3_u32*)&smem[cb], 16, 0, 0);          \
      __builtin_amdgcn_global_load_lds((as1_u32*)(gv_ + cb + l * 4),            \
                                       (as3_u32*)&smem[8192 + cb], 16, 0, 0);   \
    }                                                                           \
  }

#define K1_COMPUTE()                                                          \
  {                                                                           \
    _Pragma("unroll")                                                         \
    for (int ks = 0; ks < 4; ++ks) {                                          \
      float ak[8];                                                            \
      _Pragma("unroll")                                                       \
      for (int j = 0; j < 8; ++j)                                             \
        ak[j] = smem[(ks * 32 + 8 * g + j) * 64 + 16 * w + c];                \
      unsigned int au[4];                                                     \
      _Pragma("unroll")                                                       \
      for (int j = 0; j < 4; ++j) au[j] = packbf2(ak[2 * j], ak[2 * j + 1]);  \
      const sh8 afr = __builtin_bit_cast(sh8, *(const uint4*)au);             \
      _Pragma("unroll")                                                       \
      for (int et = 0; et < 4; ++et) {                                        \
        float bv[8];                                                          \
        _Pragma("unroll")                                                     \
        for (int j = 0; j < 8; ++j)                                           \
          bv[j] = smem[8192 + (ks * 32 + 8 * g + j) * 64 + 16 * et + c];      \
        unsigned int bu[4];                                                   \
        _Pragma("unroll")                                                     \
        for (int j = 0; j < 4; ++j) bu[j] = packbf2(bv[2 * j], bv[2 * j + 1]);\
        const sh8 bfr = __builtin_bit_cast(sh8, *(const uint4*)bu);           \
        acc[et] = __builtin_amdgcn_mfma_f32_16x16x32_bf16(afr, bfr, acc[et], 0, 0, 0); \
      }                                                                       \
    }                                                                         \
    _Pragma("unroll")                                                         \
    for (int r = 0; r < 32; ++r) zacc += (double)smem[(w * 32 + r) * 64 + l]; \
  }

  // phase 0: rows 0..127
  K1_ISSUE(0)
  asm volatile("s_waitcnt vmcnt(0)" ::: "memory");
  __builtin_amdgcn_s_barrier();
  K1_COMPUTE()

  __syncthreads();   // all waves done reading phase-0 tile

  // phase 1: rows 128..255 (same LDS)
  K1_ISSUE(1)
  asm volatile("s_waitcnt vmcnt(0)" ::: "memory");
  __builtin_amdgcn_s_barrier();
  K1_COMPUTE()
#undef K1_ISSUE
#undef K1_COMPUTE

  // Pm partial: D layout col=lane&15 -> e=16et+c, row=(lane>>4)*4+r -> d=16w+4g+r
  float* pd = Pm + ((size_t)ck * BH + bh) * MM;
  #pragma unroll
  for (int et = 0; et < 4; ++et)
    #pragma unroll
    for (int r = 0; r < 4; ++r)
      pd[(16 * w + 4 * g + r) * 64 + 16 * et + c] = acc[et][r];

  // z partial p = ck*4 + w, component d = l
  Pz[((size_t)(ck * 4 + w) * BH + bh) * Dc + l] = zacc;
}

// ---- Kernel 1 (fallback, R15 verbatim: gll 2-phase, SS=8) ----
__global__ __launch_bounds__(256) void k1_v15(const float* __restrict__ K,
                                              const float* __restrict__ V,
                                              float* __restrict__ Pm,
                                              double* __restrict__ Pz) {
  constexpr int SS = 8, CHUNK = Sc / SS, SROWS = 32, NST = CHUNK / SROWS;
  const int blk = blockIdx.x, bh = blk >> 3, ck = blk & 7;
  const int tid = threadIdx.x, w = tid >> 6, l = tid & 63;
  const int g = l >> 4, c = l & 15;
  const size_t base = ((size_t)bh * Sc + (size_t)ck * CHUNK) * Dc;
  const float* Kg = K + base;
  const float* Vg = V + base;
  __shared__ __align__(16) float smem[2 * 4096];
  const int lofs = w * 512 + l * 4;
  f32x4 acc[4];
  #pragma unroll
  for (int i = 0; i < 4; ++i) acc[i] = (f32x4){0.f, 0.f, 0.f, 0.f};
  double zacc = 0.0;
#define K1_ISSUE(T, BUF)                                                         \
  {                                                                              \
    const float* gk_ = Kg + (size_t)(T) * 2048 + lofs;                           \
    const float* gv_ = Vg + (size_t)(T) * 2048 + lofs;                           \
    float* lk_ = &smem[(BUF) * 4096 + w * 512];                                  \
    float* lv_ = &smem[(BUF) * 4096 + 2048 + w * 512];                           \
    __builtin_amdgcn_global_load_lds((as1_u32*)gk_,         (as3_u32*)lk_,         16, 0, 0); \
    __builtin_amdgcn_global_load_lds((as1_u32*)(gk_ + 256), (as3_u32*)(lk_ + 256), 16, 0, 0); \
    __builtin_amdgcn_global_load_lds((as1_u32*)gv_,         (as3_u32*)lv_,         16, 0, 0); \
    __builtin_amdgcn_global_load_lds((as1_u32*)(gv_ + 256), (as3_u32*)(lv_ + 256), 16, 0, 0); \
  }
  K1_ISSUE(0, 0)
  for (int t = 0; t < NST; ++t) {
    const int buf = t & 1;
    asm volatile("s_waitcnt vmcnt(0)" ::: "memory");
    asm volatile("s_waitcnt lgkmcnt(0)" ::: "memory");
    __builtin_amdgcn_s_barrier();
    if (t + 1 < NST) K1_ISSUE(t + 1, buf ^ 1)
    const float* bK = &smem[buf * 4096];
    const float* bV = &smem[buf * 4096 + 2048];
    #pragma unroll
    for (int r = 0; r < 8; ++r) zacc += (double)bK[(8 * w + r) * 64 + l];
    float ak[8];
    #pragma unroll
    for (int j = 0; j < 8; ++j) ak[j] = bK[(8 * g + j) * 64 + 16 * w + c];
    unsigned int au[4];
    #pragma unroll
    for (int j = 0; j < 4; ++j) au[j] = packbf2(ak[2 * j], ak[2 * j + 1]);
    const sh8 afr = __builtin_bit_cast(sh8, *(const uint4*)au);
    #pragma unroll
    for (int et = 0; et < 4; ++et) {
      float bv[8];
      #pragma unroll
      for (int j = 0; j < 8; ++j) bv[j] = bV[(8 * g + j) * 64 + 16 * et + c];
      unsigned int bu[4];
      #pragma unroll
      for (int j = 0; j < 4; ++j) bu[j] = packbf2(bv[2 * j], bv[2 * j + 1]);
      const sh8 bfr = __builtin_bit_cast(sh8, *(const uint4*)bu);
      acc[et] = __builtin_amdgcn_mfma_f32_16x16x32_bf16(afr, bfr, acc[et], 0, 0, 0);
    }
  }
#undef K1_ISSUE
  float* pd = Pm + ((size_t)ck * BH + bh) * MM;
  #pragma unroll
  for (int et = 0; et < 4; ++et)
    #pragma unroll
    for (int r = 0; r < 4; ++r)
      pd[(16 * w + 4 * g + r) * 64 + 16 * et + c] = acc[et][r];
  Pz[((size_t)(ck * 4 + w) * BH + bh) * Dc + l] = zacc;
}

// ---- Kernel 2: reduce M partials (f32); z = f64 exact sum ROUNDED TO F32 ----
__global__ __launch_bounds__(256) void k2_reduce(const float* __restrict__ Pm,
                                                 const double* __restrict__ Pz,
                                                 float* __restrict__ Fm,
                                                 float* __restrict__ Fz,
                                                 int ss, int nzp) {
  const int i = blockIdx.x * 256 + threadIdx.x;
  const int nm = BH * MM;
  if (i < nm) {
    float s = 0.f;
    for (int cc = 0; cc < ss; ++cc) s += Pm[(size_t)cc * nm + i];
    Fm[i] = s;
  }
  const int nz = BH * Dc;
  if (i < nz) {
    double s = 0.0;
    for (int cc = 0; cc < nzp; ++cc) s += Pz[(size_t)cc * nz + i];
    Fz[i] = (float)s;   // f32 intermediate matches np bitwise
  }
}

// ---- Kernel 3: out = (q @ M) / (q . z_f32 + eps); 4 rows x 8 cols per thread ----
__global__ __launch_bounds__(256) void k3_retrieve(const float* __restrict__ Q,
                                                   const float* __restrict__ Fm,
                                                   const float* __restrict__ Fz,
                                                   float* __restrict__ O) {
  const int blk = blockIdx.x;             // BH * (Sc/QT) = 128*32
  const int bh = blk >> 5;
  const int row0 = (blk & 31) * QT;

  __shared__ __align__(16) float lm[Dc][Dc];     // 16 KB
  __shared__ __align__(16) float lq[QT][68];     // padded: row stride 68 floats
  __shared__ __align__(16) float lz[Dc];         // f32 z (the np intermediate)

  const int tid = threadIdx.x;

  const float4* gm4 = (const float4*)(Fm + (size_t)bh * MM);
  float4* lm4 = (float4*)&lm[0][0];
  #pragma unroll
  for (int j = 0; j < 4; ++j) lm4[tid + j * 256] = gm4[tid + j * 256];
  if (tid < Dc) lz[tid] = Fz[(size_t)bh * Dc + tid];

  const float4* gq4 = (const float4*)(Q + ((size_t)bh * Sc + row0) * Dc);
  #pragma unroll
  for (int j = 0; j < 8; ++j) {
    const int i4 = tid + j * 256;
    const float4 v = gq4[i4];
    const int f = i4 * 4;
    *(float4*)&lq[f >> 6][f & 63] = v;
  }
  __syncthreads();

  const int rg = tid >> 3;       // 0..31 -> row quad
  const int cg = tid & 7;        // 0..7  -> 8-col block
  const int r0 = rg * 4;
  const int e0 = cg * 8;

  float acc[4][8] = {};
  double den[4] = {0.0, 0.0, 0.0, 0.0};

  #pragma unroll
  for (int ds = 0; ds < 16; ++ds) {
    const int d0 = ds * 4;
    const float4 z4 = *(const float4*)&lz[d0];
    const float* zf = (const float*)&z4;
    float4 q4[4];
    #pragma unroll
    for (int r = 0; r < 4; ++r) q4[r] = *(const float4*)&lq[r0 + r][d0];
    const float* qf[4] = {(const float*)&q4[0], (const float*)&q4[1],
                          (const float*)&q4[2], (const float*)&q4[3]};
    #pragma unroll
    for (int i = 0; i < 4; ++i) {
      const float4 ma = *(const float4*)&lm[d0 + i][e0];
      const float4 mb = *(const float4*)&lm[d0 + i][e0 + 4];
      const float mf[8] = {ma.x, ma.y, ma.z, ma.w, mb.x, mb.y, mb.z, mb.w};
      const double zd = (double)zf[i];
      #pragma unroll
      for (int r = 0; r < 4; ++r) {
        const float qs = qf[r][i];
        den[r] += (double)qs * zd;
        #pragma unroll
        for (int j = 0; j < 8; ++j)
          acc[r][j] = fmaf(qs, mf[j], acc[r][j]);
      }
    }
  }

  #pragma unroll
  for (int r = 0; r < 4; ++r) {
    const double iv = 1.0 / (den[r] + 1e-6);
    float* go = O + ((size_t)bh * Sc + row0 + r0 + r) * Dc + e0;
    ((float4*)go)[0] = make_float4((float)((double)acc[r][0] * iv),
                                   (float)((double)acc[r][1] * iv),
                                   (float)((double)acc[r][2] * iv),
                                   (float)((double)acc[r][3] * iv));
    ((float4*)go)[1] = make_float4((float)((double)acc[r][4] * iv),
                                   (float)((double)acc[r][5] * iv),
                                   (float)((double)acc[r][6] * iv),
                                   (float)((double)acc[r][7] * iv));
  }
}

extern "C" void kernel_launch(void* const* d_in, const int* in_sizes, int n_in,
                              void* d_out, int out_size, void* d_ws, size_t ws_size,
                              hipStream_t stream) {
  const float* K = (const float*)d_in[0];   // keys    [B,H,S,D]
  const float* V = (const float*)d_in[1];   // values
  const float* Q = (const float*)d_in[2];   // queries
  float* O = (float*)d_out;                 // [B,H,S,D]

  // primary path footprint (ss=16 layout, proven R14/R16-R18): ~39.9 MB
  const size_t need16 = (size_t)16 * BH * MM * 4 + (size_t)BH * MM * 4 +
                        (size_t)64 * BH * Dc * 8 + (size_t)BH * Dc * 4;
  const int ss = (ws_size >= need16) ? 16 : 8;
  const int nzp = ss * 4;

  float* Pm = (float*)d_ws;                                  // ss*BH*MM floats
  float* Fm = Pm + (size_t)ss * BH * MM;                     // BH*MM floats
  double* Pz = (double*)(Fm + (size_t)BH * MM);              // nzp*BH*Dc doubles
  float* Fz = (float*)(Pz + (size_t)nzp * BH * Dc);          // BH*Dc floats

  if (ss == 16)
    hipLaunchKernelGGL(k1_burst, dim3(BH * 16), dim3(256), 0, stream, K, V, Pm, Pz);
  else
    hipLaunchKernelGGL(k1_v15, dim3(BH * 8), dim3(256), 0, stream, K, V, Pm, Pz);
  hipLaunchKernelGGL(k2_reduce, dim3((BH * MM + 255) / 256), dim3(256), 0, stream,
                     Pm, Pz, Fm, Fz, ss, nzp);
  hipLaunchKernelGGL(k3_retrieve, dim3(BH * (Sc / QT)), dim3(256), 0, stream, Q, Fm, Fz, O);
}